// Round 2
// baseline (4762.956 us; speedup 1.0000x reference)
//
#include <hip/hip_runtime.h>

#define DIM 16
#define HID 256
#define NSTEPS 10
#define TILE_B 16
#define NTHR 512
#define LSTR 260   // 256 + 4 pad

__device__ __forceinline__ void silu_both(float x, float& h, float& d) {
    float s = 1.0f / (1.0f + __expf(-x));
    h = x * s;
    d = s * (1.0f + x * (1.0f - s));
}

// M[j][k] = W2[j][k] * sum_i W1[i][j] * W3[k][i]   (256x256, constant per launch)
__global__ void cnf_make_M(const float* __restrict__ W1, const float* __restrict__ W2,
                           const float* __restrict__ W3, float* __restrict__ M) {
    const int j = blockIdx.x;
    const int k = threadIdx.x;
    float g = 0.0f;
#pragma unroll
    for (int i = 0; i < DIM; ++i) g = fmaf(W1[i * HID + j], W3[k * DIM + i], g);
    M[j * HID + k] = W2[j * HID + k] * g;
}

__global__ __launch_bounds__(NTHR, 4) void cnf_main(
    const float* __restrict__ x,
    const float* __restrict__ W1, const float* __restrict__ b1,
    const float* __restrict__ W2, const float* __restrict__ b2,
    const float* __restrict__ W3, const float* __restrict__ b3,
    const float* __restrict__ M, float* __restrict__ out)
{
    __shared__ float h1s[TILE_B][LSTR];
    __shared__ float d1s[TILE_B][LSTR];
    __shared__ float h2s[TILE_B][LSTR];
    __shared__ float zstage[TILE_B][DIM];
    __shared__ float zbase[TILE_B][DIM];
    __shared__ float zacc[TILE_B][DIM];
    __shared__ float fzs[TILE_B][DIM];
    __shared__ float divs[TILE_B];
    __shared__ float laccs[TILE_B];
    __shared__ float logps[TILE_B];

    const int tid = (int)threadIdx.x;
    const int b0 = (int)blockIdx.x * TILE_B;
    // phase-specific thread mappings
    const int rA = tid >> 4;          // tid<256: 0..15 (DIM-wide ops)
    const int cA = tid & 15;
    const int r1 = tid >> 5;          // 0..15   phase 1: one 32-lane group per row
    const int c1 = (tid & 31) << 3;   // 0..248  8 cols/thread
    const int r2 = (tid >> 6) << 1;   // 0,2,..,14  phase 2: one wave per 2 rows
    const int c2 = (tid & 63) << 2;   // 0..252     4 cols/thread
    const int r3 = tid >> 5;          // 0..15   phase 3
    const int c3 = (tid & 31) >> 1;   // 0..15
    const int kh = tid & 1;           // k-half split

    if (tid < 256) {
        float v = x[(b0 + rA) * DIM + cA];
        zstage[rA][cA] = v;
        zbase[rA][cA] = v;
        if (cA == 0) logps[rA] = 0.0f;
    }

    const float dt = 0.1f;
    const float dt6 = dt / 6.0f;

    for (int step = 0; step < NSTEPS; ++step) {
        const float t0 = dt * (float)step;
        if (tid < 256) {
            zacc[rA][cA] = 0.0f;
            if (cA == 0) laccs[rA] = 0.0f;
        }

        for (int s = 0; s < 4; ++s) {
            const float t = t0 + ((s == 0) ? 0.0f : (s == 3) ? dt : 0.5f * dt);
            const float wst = (s == 1 || s == 2) ? 2.0f : 1.0f;
            __syncthreads();   // zstage ready; h1s/d1s free

            // ---------- phase 1: pre1 = [z, t] @ W1 + b1 -> h1 (silu), d1 (silu') ----------
            {
                float zr[DIM];
#pragma unroll
                for (int i = 0; i < DIM; ++i) zr[i] = zstage[r1][i];
#pragma unroll
                for (int g = 0; g < 8; g += 4) {
                    const int c = c1 + g;
                    float4 acc = *(const float4*)(b1 + c);
                    const float4 wt = *(const float4*)(W1 + DIM * HID + c);  // t row
                    acc.x = fmaf(t, wt.x, acc.x); acc.y = fmaf(t, wt.y, acc.y);
                    acc.z = fmaf(t, wt.z, acc.z); acc.w = fmaf(t, wt.w, acc.w);
#pragma unroll
                    for (int i = 0; i < DIM; ++i) {
                        const float4 wv = *(const float4*)(W1 + i * HID + c);
                        acc.x = fmaf(zr[i], wv.x, acc.x); acc.y = fmaf(zr[i], wv.y, acc.y);
                        acc.z = fmaf(zr[i], wv.z, acc.z); acc.w = fmaf(zr[i], wv.w, acc.w);
                    }
                    float4 hv, dv;
                    silu_both(acc.x, hv.x, dv.x); silu_both(acc.y, hv.y, dv.y);
                    silu_both(acc.z, hv.z, dv.z); silu_both(acc.w, hv.w, dv.w);
                    // lanes 0..31 of each half-wave cover one full contiguous row: no bank conflicts
                    *(float4*)&h1s[r1][c] = hv;
                    *(float4*)&d1s[r1][c] = dv;
                }
            }
            __syncthreads();   // h1s/d1s ready

            // ---------- phase 2a: pre2 = h1 @ W2 + b2 -> h2 (LDS), d2 (registers) ----------
            float d2r[2][4];
            {
                float acc[2][4];
                {
                    const float4 bb = *(const float4*)(b2 + c2);
                    acc[0][0] = bb.x; acc[0][1] = bb.y; acc[0][2] = bb.z; acc[0][3] = bb.w;
                    acc[1][0] = bb.x; acc[1][1] = bb.y; acc[1][2] = bb.z; acc[1][3] = bb.w;
                }
                const float* w2p = W2 + c2;
#pragma unroll 2
                for (int k = 0; k < HID; k += 4) {
                    float a0[4], a1[4];
                    *(float4*)a0 = *(const float4*)&h1s[r2][k];       // wave-broadcast
                    *(float4*)a1 = *(const float4*)&h1s[r2 + 1][k];
#pragma unroll
                    for (int kk = 0; kk < 4; ++kk) {
                        const float4 wv = *(const float4*)(w2p + (k + kk) * HID);
                        acc[0][0] = fmaf(a0[kk], wv.x, acc[0][0]);
                        acc[0][1] = fmaf(a0[kk], wv.y, acc[0][1]);
                        acc[0][2] = fmaf(a0[kk], wv.z, acc[0][2]);
                        acc[0][3] = fmaf(a0[kk], wv.w, acc[0][3]);
                        acc[1][0] = fmaf(a1[kk], wv.x, acc[1][0]);
                        acc[1][1] = fmaf(a1[kk], wv.y, acc[1][1]);
                        acc[1][2] = fmaf(a1[kk], wv.z, acc[1][2]);
                        acc[1][3] = fmaf(a1[kk], wv.w, acc[1][3]);
                    }
                }
#pragma unroll
                for (int rr = 0; rr < 2; ++rr) {
                    float4 hv;
                    silu_both(acc[rr][0], hv.x, d2r[rr][0]);
                    silu_both(acc[rr][1], hv.y, d2r[rr][1]);
                    silu_both(acc[rr][2], hv.z, d2r[rr][2]);
                    silu_both(acc[rr][3], hv.w, d2r[rr][3]);
                    *(float4*)&h2s[r2 + rr][c2] = hv;
                }
            }

            // ---------- phase 2b: v = d1 @ M ; div = sum(v * d2) ----------
            {
                float acc[2][4];
#pragma unroll
                for (int rr = 0; rr < 2; ++rr)
                    acc[rr][0] = acc[rr][1] = acc[rr][2] = acc[rr][3] = 0.0f;
                const float* mp = M + c2;
#pragma unroll 2
                for (int k = 0; k < HID; k += 4) {
                    float a0[4], a1[4];
                    *(float4*)a0 = *(const float4*)&d1s[r2][k];
                    *(float4*)a1 = *(const float4*)&d1s[r2 + 1][k];
#pragma unroll
                    for (int kk = 0; kk < 4; ++kk) {
                        const float4 wv = *(const float4*)(mp + (k + kk) * HID);
                        acc[0][0] = fmaf(a0[kk], wv.x, acc[0][0]);
                        acc[0][1] = fmaf(a0[kk], wv.y, acc[0][1]);
                        acc[0][2] = fmaf(a0[kk], wv.z, acc[0][2]);
                        acc[0][3] = fmaf(a0[kk], wv.w, acc[0][3]);
                        acc[1][0] = fmaf(a1[kk], wv.x, acc[1][0]);
                        acc[1][1] = fmaf(a1[kk], wv.y, acc[1][1]);
                        acc[1][2] = fmaf(a1[kk], wv.z, acc[1][2]);
                        acc[1][3] = fmaf(a1[kk], wv.w, acc[1][3]);
                    }
                }
                float p[2];
#pragma unroll
                for (int rr = 0; rr < 2; ++rr)
                    p[rr] = acc[rr][0] * d2r[rr][0] + acc[rr][1] * d2r[rr][1]
                          + acc[rr][2] * d2r[rr][2] + acc[rr][3] * d2r[rr][3];
#pragma unroll
                for (int m = 32; m >= 1; m >>= 1) {
                    p[0] += __shfl_xor(p[0], m, 64);
                    p[1] += __shfl_xor(p[1], m, 64);
                }
                if ((tid & 63) == 0) { divs[r2] = p[0]; divs[r2 + 1] = p[1]; }
            }
            __syncthreads();   // h2s, divs ready

            // ---------- phase 3: fz = h2 @ W3 + b3 (k split across lane pairs) ----------
            {
                float acc = (kh == 0) ? b3[c3] : 0.0f;
                const int kb = kh << 7;
#pragma unroll 4
                for (int k = 0; k < 128; k += 4) {
                    const float4 hv = *(const float4*)&h2s[r3][kb + k];
                    acc = fmaf(hv.x, W3[(kb + k + 0) * DIM + c3], acc);
                    acc = fmaf(hv.y, W3[(kb + k + 1) * DIM + c3], acc);
                    acc = fmaf(hv.z, W3[(kb + k + 2) * DIM + c3], acc);
                    acc = fmaf(hv.w, W3[(kb + k + 3) * DIM + c3], acc);
                }
                acc += __shfl_xor(acc, 1, 64);
                if (kh == 0) fzs[r3][c3] = acc;
            }
            __syncthreads();   // fzs ready

            // ---------- RK4 stage update ----------
            if (tid < 256) {
                const float fv = fzs[rA][cA];
                const float za = zacc[rA][cA] + wst * fv;
                zacc[rA][cA] = za;
                if (cA == 0) laccs[rA] -= wst * divs[rA];
                if (s < 3) {
                    const float coef = (s == 2) ? dt : 0.5f * dt;
                    zstage[rA][cA] = zbase[rA][cA] + coef * fv;
                } else {
                    const float zn = zbase[rA][cA] + dt6 * za;
                    zbase[rA][cA] = zn;
                    zstage[rA][cA] = zn;
                    if (cA == 0) logps[rA] += dt6 * laccs[rA];
                }
            }
        }
    }

    __syncthreads();
    if (tid < TILE_B) {
        float ss = 0.0f;
#pragma unroll
        for (int i = 0; i < DIM; ++i) { const float zv = zbase[tid][i]; ss = fmaf(zv, zv, ss); }
        out[b0 + tid] = -0.5f * (ss + (float)DIM * 1.8378770664093453f) - logps[tid];
    }
}

extern "C" void kernel_launch(void* const* d_in, const int* in_sizes, int n_in,
                              void* d_out, int out_size, void* d_ws, size_t ws_size,
                              hipStream_t stream) {
    (void)in_sizes; (void)n_in; (void)out_size; (void)ws_size;
    const float* x  = (const float*)d_in[0];
    const float* W1 = (const float*)d_in[1];
    const float* b1 = (const float*)d_in[2];
    const float* W2 = (const float*)d_in[3];
    const float* b2 = (const float*)d_in[4];
    const float* W3 = (const float*)d_in[5];
    const float* b3 = (const float*)d_in[6];
    float* M = (float*)d_ws;   // 256*256*4 = 256 KB scratch

    cnf_make_M<<<HID, HID, 0, stream>>>(W1, W2, W3, M);
    cnf_main<<<8192 / TILE_B, NTHR, 0, stream>>>(x, W1, b1, W2, b2, W3, b3, M, (float*)d_out);
}

// Round 3
// 504.546 us; speedup vs baseline: 9.4401x; 9.4401x over previous
//
#include <hip/hip_runtime.h>

#define DIM 16
#define HID 256
#define NSTEPS 10
#define TILE_B 32
#define NTHR 512
#define LSH 264      // bf16 LDS row stride for 256-wide tiles (+8 shorts = 16B pad)

typedef __attribute__((ext_vector_type(8))) short bf16x8;
typedef __attribute__((ext_vector_type(4))) float f32x4;

__device__ __forceinline__ unsigned short f2bf(float f) {
    unsigned u = __float_as_uint(f);
    u += 0x7fff + ((u >> 16) & 1);          // RNE
    return (unsigned short)(u >> 16);
}
__device__ __forceinline__ void silu_both(float x, float& h, float& d) {
    float s = 1.0f / (1.0f + __expf(-x));
    h = x * s;
    d = s * (1.0f + x * (1.0f - s));
}

// w2t[n][j] = bf16(W2[j][n]);  mt[n][j] = bf16(M[j][n]), M[j][n] = W2[j][n]*sum_i W1[i][j]*W3[n][i]
__global__ void cnf_setup(const float* __restrict__ W1, const float* __restrict__ W2,
                          const float* __restrict__ W3,
                          unsigned short* __restrict__ w2t, unsigned short* __restrict__ mt) {
    const int j = blockIdx.x;      // GEMM K index (W2 row)
    const int n = threadIdx.x;     // GEMM N index
    float g = 0.0f;
#pragma unroll
    for (int i = 0; i < DIM; ++i) g = fmaf(W1[i * HID + j], W3[n * DIM + i], g);
    const float w2 = W2[j * HID + n];            // coalesced over n
    w2t[n * HID + j] = f2bf(w2);
    mt [n * HID + j] = f2bf(w2 * g);
}

__global__ __launch_bounds__(NTHR, 2) void cnf_main(
    const float* __restrict__ x,
    const float* __restrict__ W1, const float* __restrict__ b1,
    const float* __restrict__ b2, const float* __restrict__ b3,
    const unsigned short* __restrict__ w2t, const unsigned short* __restrict__ mt,
    const float* __restrict__ W3, float* __restrict__ out)
{
    __shared__ unsigned short zb[TILE_B][16];      // z state, bf16 A-layout (K=16, rest zero-fragged)
    __shared__ unsigned short w1t[HID][16];        // W1^T bf16 (k<16; t-row folded into bias)
    __shared__ unsigned short w3t[DIM][LSH];       // W3^T bf16 [n][k]
    __shared__ unsigned short h1s[TILE_B][LSH];    // h1 bf16
    __shared__ unsigned short d1h2[TILE_B][LSH];   // d1 bf16, ALIASED to h2 after mid-P2 barrier
    __shared__ float fzp[4][TILE_B][DIM];          // phase-3 partials (k-quarters)
    __shared__ float divp[8][TILE_B];              // per-wave divergence partials

    const int tid  = (int)threadIdx.x;
    const int lane = tid & 63;
    const int wv   = tid >> 6;            // 0..7
    const int g    = lane >> 4;           // quad 0..3
    const int r    = lane & 15;
    const int b0   = (int)blockIdx.x * TILE_B;
    const int n0   = wv * 32;             // this wave's 32-col slice
    const int row_u = tid >> 4, col_u = tid & 15;   // update-phase mapping (32x16)

    // ---- one-time LDS builds ----
    {   // W1^T: w1t[n][k] = bf16(W1[k][n]), k<16
        const int n = tid >> 1, kh = (tid & 1) * 8;
#pragma unroll
        for (int k = 0; k < 8; ++k) w1t[n][kh + k] = f2bf(W1[(kh + k) * HID + n]);
    }
    {   // W3^T: w3t[n][k] = bf16(W3[k][n])
        const int n = tid >> 5, k0 = (tid & 31) * 8;
#pragma unroll
        for (int j = 0; j < 8; ++j) w3t[n][k0 + j] = f2bf(W3[(k0 + j) * DIM + n]);
    }
    // ---- z state: one element per thread, fp32 in registers ----
    float zbase = x[(b0 + row_u) * DIM + col_u];
    float zacc = 0.0f, lacc = 0.0f, logp = 0.0f;
    zb[row_u][col_u] = f2bf(zbase);

    const float dt = 0.1f, dt6 = dt / 6.0f;
    float tcur = 0.0f;   // wave-uniform stage time

    for (int it = 0; it < NSTEPS * 4; ++it) {
        const int s = it & 3;
        const int step = it >> 2;
        const float t0 = dt * (float)step;
        const float wst = (s == 1 || s == 2) ? 2.0f : 1.0f;
        __syncthreads();   // zb (and first pass: w1t/w3t) ready

        // ---------- phase 1 (MFMA): pre1 = [z,t]@W1+b1 -> h1,d1 bf16 ----------
        {
            bf16x8 az[2], bw[2];
            const bf16x8 zf = {0,0,0,0,0,0,0,0};
#pragma unroll
            for (int rt = 0; rt < 2; ++rt)
                az[rt] = (g < 2) ? *(const bf16x8*)&zb[rt * 16 + r][g * 8] : zf;
#pragma unroll
            for (int ct = 0; ct < 2; ++ct)
                bw[ct] = (g < 2) ? *(const bf16x8*)&w1t[n0 + ct * 16 + r][g * 8] : zf;
#pragma unroll
            for (int ct = 0; ct < 2; ++ct) {
                const int n = n0 + ct * 16 + r;
                const float bb = fmaf(tcur, W1[DIM * HID + n], b1[n]);  // fold t-row into bias
#pragma unroll
                for (int rt = 0; rt < 2; ++rt) {
                    f32x4 c = {0.f, 0.f, 0.f, 0.f};
                    c = __builtin_amdgcn_mfma_f32_16x16x32_bf16(az[rt], bw[ct], c, 0, 0, 0);
#pragma unroll
                    for (int q = 0; q < 4; ++q) {
                        float h, d;
                        silu_both(c[q] + bb, h, d);
                        h1s [rt * 16 + g * 4 + q][n] = f2bf(h);
                        d1h2[rt * 16 + g * 4 + q][n] = f2bf(d);
                    }
                }
            }
        }
        __syncthreads();   // h1/d1 ready

        // ---------- phase 2 (MFMA): pre2 = h1@W2 ; v = d1@M ----------
        {
            f32x4 c2[2][2], cv[2][2];
#pragma unroll
            for (int a = 0; a < 2; ++a)
#pragma unroll
                for (int b = 0; b < 2; ++b) {
                    c2[a][b] = (f32x4){0.f, 0.f, 0.f, 0.f};
                    cv[a][b] = (f32x4){0.f, 0.f, 0.f, 0.f};
                }
#pragma unroll 2
            for (int k = 0; k < 8; ++k) {
                bf16x8 ah[2], ad[2], bwv[2], bmv[2];
#pragma unroll
                for (int rt = 0; rt < 2; ++rt) {
                    ah[rt] = *(const bf16x8*)&h1s [rt * 16 + r][k * 32 + g * 8];
                    ad[rt] = *(const bf16x8*)&d1h2[rt * 16 + r][k * 32 + g * 8];
                }
#pragma unroll
                for (int ct = 0; ct < 2; ++ct) {
                    const long boff = (long)(n0 + ct * 16 + r) * HID + k * 32 + g * 8;
                    bwv[ct] = *(const bf16x8*)(w2t + boff);
                    bmv[ct] = *(const bf16x8*)(mt + boff);
                }
#pragma unroll
                for (int rt = 0; rt < 2; ++rt)
#pragma unroll
                    for (int ct = 0; ct < 2; ++ct) {
                        c2[rt][ct] = __builtin_amdgcn_mfma_f32_16x16x32_bf16(ah[rt], bwv[ct], c2[rt][ct], 0, 0, 0);
                        cv[rt][ct] = __builtin_amdgcn_mfma_f32_16x16x32_bf16(ad[rt], bmv[ct], cv[rt][ct], 0, 0, 0);
                    }
            }
            __syncthreads();   // all waves done READING d1h2 -> safe to overwrite with h2

            float p[2][4];
#pragma unroll
            for (int rt = 0; rt < 2; ++rt)
#pragma unroll
                for (int q = 0; q < 4; ++q) p[rt][q] = 0.0f;
#pragma unroll
            for (int ct = 0; ct < 2; ++ct) {
                const int n = n0 + ct * 16 + r;
                const float bb = b2[n];
#pragma unroll
                for (int rt = 0; rt < 2; ++rt)
#pragma unroll
                    for (int q = 0; q < 4; ++q) {
                        float h, d;
                        silu_both(c2[rt][ct][q] + bb, h, d);
                        d1h2[rt * 16 + g * 4 + q][n] = f2bf(h);        // h2 (aliased)
                        p[rt][q] = fmaf(d, cv[rt][ct][q], p[rt][q]);   // d2 .* v
                    }
            }
#pragma unroll
            for (int m = 1; m < 16; m <<= 1)
#pragma unroll
                for (int rt = 0; rt < 2; ++rt)
#pragma unroll
                    for (int q = 0; q < 4; ++q) p[rt][q] += __shfl_xor(p[rt][q], m, 64);
            if (r == 0)
#pragma unroll
                for (int rt = 0; rt < 2; ++rt)
#pragma unroll
                    for (int q = 0; q < 4; ++q) divp[wv][rt * 16 + g * 4 + q] = p[rt][q];
        }
        __syncthreads();   // h2, divp ready

        // ---------- phase 3 (MFMA): fz = h2@W3 (k split 4 ways across wave pairs) ----------
        {
            const int rt = wv & 1, q3 = wv >> 1;   // row-tile, k-quarter
            f32x4 c3 = {0.f, 0.f, 0.f, 0.f};
#pragma unroll
            for (int ki = 0; ki < 2; ++ki) {
                const int kk = q3 * 64 + ki * 32 + g * 8;
                bf16x8 a = *(const bf16x8*)&d1h2[rt * 16 + r][kk];
                bf16x8 b = *(const bf16x8*)&w3t[r][kk];
                c3 = __builtin_amdgcn_mfma_f32_16x16x32_bf16(a, b, c3, 0, 0, 0);
            }
#pragma unroll
            for (int q = 0; q < 4; ++q) fzp[q3][rt * 16 + g * 4 + q][r] = c3[q];
        }
        __syncthreads();   // fzp ready

        // ---------- RK4 stage update (fp32, registers) ----------
        {
            const float fz = b3[col_u] + fzp[0][row_u][col_u] + fzp[1][row_u][col_u]
                           + fzp[2][row_u][col_u] + fzp[3][row_u][col_u];
            zacc = fmaf(wst, fz, zacc);
            float znext;
            if (s < 3) {
                const float coef = (s == 2) ? dt : 0.5f * dt;
                znext = fmaf(coef, fz, zbase);
                tcur = t0 + ((s == 2) ? dt : 0.5f * dt);
            } else {
                zbase = fmaf(dt6, zacc, zbase);
                znext = zbase;
                zacc = 0.0f;
                tcur = t0 + dt;
            }
            zb[row_u][col_u] = f2bf(znext);
            if (col_u == 0) {
                float dv = 0.0f;
#pragma unroll
                for (int w = 0; w < 8; ++w) dv += divp[w][row_u];
                lacc = fmaf(-wst, dv, lacc);
                if (s == 3) { logp = fmaf(dt6, lacc, logp); lacc = 0.0f; }
            }
        }
    }

    // ---------- epilogue: logpz - logp1 ----------
    float ss = zbase * zbase;
#pragma unroll
    for (int m = 1; m < 16; m <<= 1) ss += __shfl_xor(ss, m, 64);
    if (col_u == 0)
        out[b0 + row_u] = -0.5f * (ss + (float)DIM * 1.8378770664093453f) - logp;
}

extern "C" void kernel_launch(void* const* d_in, const int* in_sizes, int n_in,
                              void* d_out, int out_size, void* d_ws, size_t ws_size,
                              hipStream_t stream) {
    (void)in_sizes; (void)n_in; (void)out_size; (void)ws_size;
    const float* x  = (const float*)d_in[0];
    const float* W1 = (const float*)d_in[1];
    const float* b1 = (const float*)d_in[2];
    const float* W2 = (const float*)d_in[3];
    const float* b2 = (const float*)d_in[4];
    const float* W3 = (const float*)d_in[5];
    const float* b3 = (const float*)d_in[6];
    unsigned short* w2t = (unsigned short*)d_ws;               // 128 KB
    unsigned short* mt  = w2t + HID * HID;                     // 128 KB

    cnf_setup<<<HID, HID, 0, stream>>>(W1, W2, W3, w2t, mt);
    cnf_main<<<8192 / TILE_B, NTHR, 0, stream>>>(x, W1, b1, b2, b3, w2t, mt, W3, (float*)d_out);
}